// Round 1
// baseline (1070.508 us; speedup 1.0000x reference)
//
#include <hip/hip_runtime.h>
#include <hip/hip_bf16.h>
#include <math.h>

#define B_    4
#define CIN   128
#define NPTS  2048
#define DIM   256
#define PH    64
#define HIDN  1024
#define KNN_  16
#define BN    (B_*NPTS)      /* 8192  */
#define CC    (BN*KNN_)      /* 131072 */
#define EPS_  1e-5f

typedef __bf16 bf16;
typedef __bf16 bf16x8 __attribute__((ext_vector_type(8)));
typedef float  f32x4  __attribute__((ext_vector_type(4)));

// ---------------------------------------------------------------------------
// prep: fp32->bf16 weight conversion + batchnorm scale/shift folding
// ---------------------------------------------------------------------------
__global__ __launch_bounds__(256) void prep_kernel(
    const float* __restrict__ ls_w, const float* __restrict__ kw,
    const float* __restrict__ qw,   const float* __restrict__ vw,
    const float* __restrict__ pw2,  const float* __restrict__ aw1,
    const float* __restrict__ aw2,  const float* __restrict__ lw,
    const float* __restrict__ pb1,  const float* __restrict__ pg,
    const float* __restrict__ pbeta,const float* __restrict__ pmean,
    const float* __restrict__ pvar,
    const float* __restrict__ ab1,  const float* __restrict__ ag,
    const float* __restrict__ abeta,const float* __restrict__ amean,
    const float* __restrict__ avar,
    bf16* ls_wb, bf16* kwb, bf16* qwb, bf16* vwb,
    bf16* pw2b, bf16* aw1b, bf16* aw2b, bf16* lwb,
    float* pe_scale, float* pe_shift, float* at_scale, float* at_shift)
{
  long e = (long)blockIdx.x * 256 + threadIdx.x;
  if (e < 32768)  { ls_wb[e] = (bf16)ls_w[e]; return; } e -= 32768;
  if (e < 65536)  { kwb[e]   = (bf16)kw[e];   return; } e -= 65536;
  if (e < 65536)  { qwb[e]   = (bf16)qw[e];   return; } e -= 65536;
  if (e < 65536)  { vwb[e]   = (bf16)vw[e];   return; } e -= 65536;
  if (e < 16384)  { pw2b[e]  = (bf16)pw2[e];  return; } e -= 16384;
  if (e < 262144) { aw1b[e]  = (bf16)aw1[e];  return; } e -= 262144;
  if (e < 262144) { aw2b[e]  = (bf16)aw2[e];  return; } e -= 262144;
  if (e < 32768)  { lwb[e]   = (bf16)lw[e];   return; } e -= 32768;
  if (e < 64) {
    float sc = pg[e] * rsqrtf(pvar[e] + EPS_);
    pe_scale[e] = sc;
    pe_shift[e] = sc * pb1[e] + pbeta[e] - pmean[e] * sc;
    return;
  } e -= 64;
  if (e < 1024) {
    float sc = ag[e] * rsqrtf(avar[e] + EPS_);
    at_scale[e] = sc;
    at_shift[e] = sc * ab1[e] + abeta[e] - amean[e] * sc;
  }
}

// ---------------------------------------------------------------------------
// transpose x (B,CIN,N) fp32 -> xT (BN, CIN) bf16  (channel-last)
// ---------------------------------------------------------------------------
__global__ __launch_bounds__(256) void transpose_x_kernel(
    const float* __restrict__ x, bf16* __restrict__ xT)
{
  long e = (long)blockIdx.x * 256 + threadIdx.x;   // over BN*CIN
  int ch = (int)(e & (CIN - 1));
  long i = e >> 7;
  int n = (int)(i & (NPTS - 1));
  int b = (int)(i >> 11);
  xT[e] = (bf16)x[((long)b * CIN + ch) * NPTS + n];
}

// ---------------------------------------------------------------------------
// KNN: one block per query point; dist formula matches reference
// ---------------------------------------------------------------------------
__global__ __launch_bounds__(256) void knn_kernel(
    const float* __restrict__ pos, int* __restrict__ idx_out)
{
  __shared__ float px[NPTS], py[NPTS], pz[NPTS], dist[NPTS];
  __shared__ float sv[256];
  __shared__ int   si[256];
  int t = threadIdx.x;
  int bn = blockIdx.x;
  int b = bn >> 11;
  int i = bn & (NPTS - 1);
  const float* p = pos + (long)b * 3 * NPTS;
  for (int j = t; j < NPTS; j += 256) {
    px[j] = p[j]; py[j] = p[NPTS + j]; pz[j] = p[2 * NPTS + j];
  }
  __syncthreads();
  float qx = px[i], qy = py[i], qz = pz[i];
  float qs = qx * qx + qy * qy + qz * qz;
  for (int j = t; j < NPTS; j += 256) {
    float s2 = px[j] * px[j] + py[j] * py[j] + pz[j] * pz[j];
    float dt = qx * px[j] + qy * py[j] + qz * pz[j];
    dist[j] = qs + s2 - 2.f * dt;
  }
  __syncthreads();
  for (int r = 0; r < KNN_; ++r) {
    float best = 1e30f; int bi = NPTS;
    for (int j = t; j < NPTS; j += 256) {
      float d = dist[j];
      if (d < best) { best = d; bi = j; }
    }
    sv[t] = best; si[t] = bi;
    __syncthreads();
    for (int s = 128; s > 0; s >>= 1) {
      if (t < s) {
        if (sv[t + s] < sv[t] || (sv[t + s] == sv[t] && si[t + s] < si[t])) {
          sv[t] = sv[t + s]; si[t] = si[t + s];
        }
      }
      __syncthreads();
    }
    if (t == 0) {
      idx_out[(long)bn * KNN_ + r] = si[0];
      dist[si[0]] = 1e30f;
    }
    __syncthreads();
  }
}

// ---------------------------------------------------------------------------
// generic channel-last GEMM: out[i][o] = sum_k inT[i][k]*W[o][k] + bias[o]
// no LDS; MFMA frags loaded directly from global (weights L2-hot).
// block tile 64x64, 4 waves each 32x32 (2x2 MFMA frags). KD multiple of 32.
// ---------------------------------------------------------------------------
template<int KD, bool OBF16>
__global__ __launch_bounds__(256) void gemmT_kernel(
    const bf16* __restrict__ inT, const bf16* __restrict__ Wb,
    const float* __restrict__ bias, void* __restrict__ outp, int O)
{
  const int tid = threadIdx.x;
  const int lane = tid & 63, wave = tid >> 6;
  const int row16 = lane & 15, grp = lane >> 4;
  const long i0 = (long)blockIdx.x * 64 + (wave & 1) * 32;
  const long o0 = (long)blockIdx.y * 64 + (wave >> 1) * 32;
  f32x4 acc[2][2] = {};
  const bf16* a0p = inT + (i0 + row16) * KD + grp * 8;
  const bf16* a1p = a0p + 16 * KD;
  const bf16* b0p = Wb + (o0 + row16) * KD + grp * 8;
  const bf16* b1p = b0p + 16 * KD;
#pragma unroll
  for (int ks = 0; ks < KD / 32; ++ks) {
    bf16x8 a0 = *(const bf16x8*)(a0p + ks * 32);
    bf16x8 a1 = *(const bf16x8*)(a1p + ks * 32);
    bf16x8 b0 = *(const bf16x8*)(b0p + ks * 32);
    bf16x8 b1 = *(const bf16x8*)(b1p + ks * 32);
    acc[0][0] = __builtin_amdgcn_mfma_f32_16x16x32_bf16(a0, b0, acc[0][0], 0, 0, 0);
    acc[0][1] = __builtin_amdgcn_mfma_f32_16x16x32_bf16(a0, b1, acc[0][1], 0, 0, 0);
    acc[1][0] = __builtin_amdgcn_mfma_f32_16x16x32_bf16(a1, b0, acc[1][0], 0, 0, 0);
    acc[1][1] = __builtin_amdgcn_mfma_f32_16x16x32_bf16(a1, b1, acc[1][1], 0, 0, 0);
  }
#pragma unroll
  for (int ot = 0; ot < 2; ++ot) {
    long o = o0 + ot * 16 + row16;
    float bv = bias[o];
#pragma unroll
    for (int it = 0; it < 2; ++it) {
#pragma unroll
      for (int r = 0; r < 4; ++r) {
        long i = i0 + it * 16 + grp * 4 + r;
        float v = acc[it][ot][r] + bv;
        if (OBF16) ((bf16*)outp)[i * O + o] = (bf16)v;
        else       ((float*)outp)[i * O + o] = v;
      }
    }
  }
}

// ---------------------------------------------------------------------------
// pe hidden layer: hidT[c][j] = relu(bn(pw1 . pos_rel)), c=(bn,k), j<64
// ---------------------------------------------------------------------------
__global__ __launch_bounds__(64) void pe_hidden_kernel(
    const float* __restrict__ pos, const int* __restrict__ idx,
    const float* __restrict__ pw1,
    const float* __restrict__ pe_scale, const float* __restrict__ pe_shift,
    bf16* __restrict__ hidT)
{
  int bn = blockIdx.x;
  int b = bn >> 11;
  int n = bn & (NPTS - 1);
  int j = threadIdx.x;
  const float* p = pos + (long)b * 3 * NPTS;
  float qx = p[n], qy = p[NPTS + n], qz = p[2 * NPTS + n];
  float w0 = pw1[j * 3], w1 = pw1[j * 3 + 1], w2 = pw1[j * 3 + 2];
  float sc = pe_scale[j], sh = pe_shift[j];
#pragma unroll
  for (int k = 0; k < KNN_; ++k) {
    int nb = idx[(long)bn * KNN_ + k];
    float rx = qx - p[nb], ry = qy - p[NPTS + nb], rz = qz - p[2 * NPTS + nb];
    float v = w0 * rx + w1 * ry + w2 * rz;
    v = sc * v + sh;
    v = v > 0.f ? v : 0.f;
    hidT[((long)bn * KNN_ + k) * PH + j] = (bf16)v;
  }
}

// ---------------------------------------------------------------------------
// uT[c][ch] = query[bn][ch] - key[(b,idx[c])][ch] + pe[c][ch]
// ---------------------------------------------------------------------------
__global__ __launch_bounds__(256) void u_kernel(
    const bf16* __restrict__ qT, const bf16* __restrict__ kT,
    const bf16* __restrict__ peT, const int* __restrict__ idx,
    bf16* __restrict__ uT)
{
  long c = blockIdx.x;              // one column per block (256 ch threads)
  int ch = threadIdx.x;
  long bn = c >> 4;
  int b = (int)(bn >> 11);
  int nb = idx[c];
  long e = c * DIM + ch;
  float v = (float)qT[bn * DIM + ch] - (float)kT[((long)b * NPTS + nb) * DIM + ch]
          + (float)peT[e];
  uT[e] = (bf16)v;
}

// ---------------------------------------------------------------------------
// fused attention MLP: attnT = ab2 + aw2 . relu(bn(aw1 . uT))
// block = 64 columns, 4 waves. HID chunked 16x64 through LDS t-buffer.
// attnT may alias uT (all reads precede the epilogue stores, rows disjoint
// across blocks).
// ---------------------------------------------------------------------------
__global__ __launch_bounds__(256) void attn_mlp_kernel(
    const bf16* __restrict__ uT, const bf16* __restrict__ aw1b,
    const bf16* __restrict__ aw2b,
    const float* __restrict__ at_scale, const float* __restrict__ at_shift,
    const float* __restrict__ ab2, bf16* __restrict__ attnT)
{
  __shared__ __align__(16) bf16 t_lds[64][72];   // +8 pad
  const int tid = threadIdx.x;
  const int lane = tid & 63, wave = tid >> 6;
  const int row16 = lane & 15, grp = lane >> 4;
  const long c0 = (long)blockIdx.x * 64;
  const int cs = wave * 16;          // GEMM1 c-slab of this wave
  const int os = wave * 64;          // GEMM2 o-slab of this wave
  f32x4 acc2[4][4] = {};
  const bf16* urow = uT + (c0 + cs + row16) * DIM + grp * 8;

  for (int jc = 0; jc < 16; ++jc) {
    const int j0 = jc * 64;
    // ---- GEMM1: t[cs..cs+16][j0..j0+64] = relu(bn(aw1 . u)) ----
    f32x4 acc1[4] = {};
#pragma unroll
    for (int ks = 0; ks < 8; ++ks) {
      bf16x8 a = *(const bf16x8*)(urow + ks * 32);
#pragma unroll
      for (int jt = 0; jt < 4; ++jt) {
        bf16x8 b = *(const bf16x8*)(aw1b + (long)(j0 + jt * 16 + row16) * DIM + ks * 32 + grp * 8);
        acc1[jt] = __builtin_amdgcn_mfma_f32_16x16x32_bf16(a, b, acc1[jt], 0, 0, 0);
      }
    }
#pragma unroll
    for (int jt = 0; jt < 4; ++jt) {
      int jg = j0 + jt * 16 + row16;
      float sc = at_scale[jg], sh = at_shift[jg];
#pragma unroll
      for (int r = 0; r < 4; ++r) {
        float v = sc * acc1[jt][r] + sh;
        v = v > 0.f ? v : 0.f;
        t_lds[cs + grp * 4 + r][jt * 16 + row16] = (bf16)v;
      }
    }
    __syncthreads();
    // ---- GEMM2: acc2[c][o] += t[c][j] * aw2[o][j] ----
#pragma unroll
    for (int ks2 = 0; ks2 < 2; ++ks2) {
      bf16x8 a2[4];
#pragma unroll
      for (int ct = 0; ct < 4; ++ct)
        a2[ct] = *(const bf16x8*)(&t_lds[ct * 16 + row16][ks2 * 32 + grp * 8]);
#pragma unroll
      for (int ot = 0; ot < 4; ++ot) {
        bf16x8 b2 = *(const bf16x8*)(aw2b + (long)(os + ot * 16 + row16) * HIDN + j0 + ks2 * 32 + grp * 8);
#pragma unroll
        for (int ct = 0; ct < 4; ++ct)
          acc2[ct][ot] = __builtin_amdgcn_mfma_f32_16x16x32_bf16(a2[ct], b2, acc2[ct][ot], 0, 0, 0);
      }
    }
    __syncthreads();
  }
  // epilogue: + ab2, store bf16
#pragma unroll
  for (int ot = 0; ot < 4; ++ot) {
    int o = os + ot * 16 + row16;
    float bv = ab2[o];
#pragma unroll
    for (int ct = 0; ct < 4; ++ct) {
#pragma unroll
      for (int r = 0; r < 4; ++r) {
        long c = c0 + ct * 16 + grp * 4 + r;
        attnT[c * DIM + o] = (bf16)(acc2[ct][ot][r] + bv);
      }
    }
  }
}

// ---------------------------------------------------------------------------
// softmax over K + aggregation: aggT[bn][o] = sum_k softmax(attn)[k]*(v+pe)
// ---------------------------------------------------------------------------
__global__ __launch_bounds__(256) void softmax_agg_kernel(
    const bf16* __restrict__ attnT, const bf16* __restrict__ peT,
    const float* __restrict__ vT, const int* __restrict__ idx,
    bf16* __restrict__ aggT)
{
  long bn = blockIdx.x;
  int b = (int)(bn >> 11);
  int o = threadIdx.x;
  float l[KNN_];
  float m = -1e30f;
#pragma unroll
  for (int k = 0; k < KNN_; ++k) {
    l[k] = (float)attnT[(bn * KNN_ + k) * DIM + o];
    m = fmaxf(m, l[k]);
  }
  float s = 0.f;
#pragma unroll
  for (int k = 0; k < KNN_; ++k) { l[k] = expf(l[k] - m); s += l[k]; }
  float inv = 1.f / s;
  float agg = 0.f;
#pragma unroll
  for (int k = 0; k < KNN_; ++k) {
    int nb = idx[bn * KNN_ + k];
    float vg = vT[((long)b * NPTS + nb) * DIM + o] + (float)peT[(bn * KNN_ + k) * DIM + o];
    agg += l[k] * inv * vg;
  }
  aggT[bn * DIM + o] = (bf16)agg;
}

// ---------------------------------------------------------------------------
// final: out[b][o][n] = lw . agg + lb + identity  (fp32, channel-major out)
// ---------------------------------------------------------------------------
__global__ __launch_bounds__(256) void final_kernel(
    const bf16* __restrict__ aggT, const bf16* __restrict__ lwb,
    const float* __restrict__ lb, const float* __restrict__ x,
    float* __restrict__ out)
{
  const int tid = threadIdx.x;
  const int lane = tid & 63, wave = tid >> 6;
  const int row16 = lane & 15, grp = lane >> 4;
  const long i0 = (long)blockIdx.x * 64 + (wave & 1) * 32;
  const int o0 = blockIdx.y * 64 + (wave >> 1) * 32;
  f32x4 acc[2][2] = {};
  const bf16* a0p = aggT + (i0 + row16) * DIM + grp * 8;
  const bf16* a1p = a0p + 16 * DIM;
  const bf16* b0p = lwb + (long)(o0 + row16) * DIM + grp * 8;
  const bf16* b1p = b0p + 16 * DIM;
#pragma unroll
  for (int ks = 0; ks < 8; ++ks) {
    bf16x8 a0 = *(const bf16x8*)(a0p + ks * 32);
    bf16x8 a1 = *(const bf16x8*)(a1p + ks * 32);
    bf16x8 b0 = *(const bf16x8*)(b0p + ks * 32);
    bf16x8 b1 = *(const bf16x8*)(b1p + ks * 32);
    acc[0][0] = __builtin_amdgcn_mfma_f32_16x16x32_bf16(a0, b0, acc[0][0], 0, 0, 0);
    acc[0][1] = __builtin_amdgcn_mfma_f32_16x16x32_bf16(a0, b1, acc[0][1], 0, 0, 0);
    acc[1][0] = __builtin_amdgcn_mfma_f32_16x16x32_bf16(a1, b0, acc[1][0], 0, 0, 0);
    acc[1][1] = __builtin_amdgcn_mfma_f32_16x16x32_bf16(a1, b1, acc[1][1], 0, 0, 0);
  }
#pragma unroll
  for (int ot = 0; ot < 2; ++ot) {
    int o = o0 + ot * 16 + row16;
    float bv = lb[o];
#pragma unroll
    for (int it = 0; it < 2; ++it) {
#pragma unroll
      for (int r = 0; r < 4; ++r) {
        long i = i0 + it * 16 + grp * 4 + r;
        int b = (int)(i >> 11);
        int n = (int)(i & (NPTS - 1));
        long off = ((long)b * CIN + o) * NPTS + n;
        out[off] = acc[it][ot][r] + bv + x[off];
      }
    }
  }
}

// ---------------------------------------------------------------------------
extern "C" void kernel_launch(void* const* d_in, const int* in_sizes, int n_in,
                              void* d_out, int out_size, void* d_ws, size_t ws_size,
                              hipStream_t stream)
{
  const float* x     = (const float*)d_in[0];
  const float* pos   = (const float*)d_in[1];
  const float* ls_w  = (const float*)d_in[2];
  const float* ls_b  = (const float*)d_in[3];
  const float* kw    = (const float*)d_in[4];
  const float* kb    = (const float*)d_in[5];
  const float* qw    = (const float*)d_in[6];
  const float* qb    = (const float*)d_in[7];
  const float* vw    = (const float*)d_in[8];
  const float* vb    = (const float*)d_in[9];
  const float* pw1   = (const float*)d_in[10];
  const float* pb1   = (const float*)d_in[11];
  const float* pg    = (const float*)d_in[12];
  const float* pbeta = (const float*)d_in[13];
  const float* pmean = (const float*)d_in[14];
  const float* pvar  = (const float*)d_in[15];
  const float* pw2   = (const float*)d_in[16];
  const float* pb2   = (const float*)d_in[17];
  const float* aw1   = (const float*)d_in[18];
  const float* ab1   = (const float*)d_in[19];
  const float* ag    = (const float*)d_in[20];
  const float* abeta = (const float*)d_in[21];
  const float* amean = (const float*)d_in[22];
  const float* avar  = (const float*)d_in[23];
  const float* aw2   = (const float*)d_in[24];
  const float* ab2   = (const float*)d_in[25];
  const float* lw    = (const float*)d_in[26];
  const float* lb    = (const float*)d_in[27];

  char* ws = (char*)d_ws;
  size_t off = 0;
  auto alloc = [&](size_t bytes) -> void* {
    void* p = ws + off;
    off = (off + bytes + 255) & ~(size_t)255;
    return p;
  };

  bf16* ls_wb = (bf16*)alloc(32768 * 2);
  bf16* kwb   = (bf16*)alloc(65536 * 2);
  bf16* qwb   = (bf16*)alloc(65536 * 2);
  bf16* vwb   = (bf16*)alloc(65536 * 2);
  bf16* pw2b  = (bf16*)alloc(16384 * 2);
  bf16* aw1b  = (bf16*)alloc(262144 * 2);
  bf16* aw2b  = (bf16*)alloc(262144 * 2);
  bf16* lwb   = (bf16*)alloc(32768 * 2);
  float* pe_scale = (float*)alloc(64 * 4);
  float* pe_shift = (float*)alloc(64 * 4);
  float* at_scale = (float*)alloc(1024 * 4);
  float* at_shift = (float*)alloc(1024 * 4);
  int*  idx  = (int*)alloc((size_t)CC * 4);
  bf16* xT   = (bf16*)alloc((size_t)BN * CIN * 2);
  bf16* hT   = (bf16*)alloc((size_t)BN * DIM * 2);
  bf16* qT   = (bf16*)alloc((size_t)BN * DIM * 2);
  bf16* kT   = (bf16*)alloc((size_t)BN * DIM * 2);
  float* vT  = (float*)alloc((size_t)BN * DIM * 4);
  bf16* hidT = (bf16*)alloc((size_t)CC * PH * 2);
  bf16* peT  = (bf16*)alloc((size_t)CC * DIM * 2);
  bf16* uT   = (bf16*)alloc((size_t)CC * DIM * 2);
  bf16* attnT = uT;  // alias: attn_mlp reads its uT rows before storing
  bf16* aggT = (bf16*)alloc((size_t)BN * DIM * 2);

  // 1. prep (converts + bn folding): 802816 + 64 + 1024 = 803904 elems
  prep_kernel<<<dim3((803904 + 255) / 256), 256, 0, stream>>>(
      ls_w, kw, qw, vw, pw2, aw1, aw2, lw,
      pb1, pg, pbeta, pmean, pvar, ab1, ag, abeta, amean, avar,
      ls_wb, kwb, qwb, vwb, pw2b, aw1b, aw2b, lwb,
      pe_scale, pe_shift, at_scale, at_shift);

  // 2. transpose x -> xT (channel-last bf16)
  transpose_x_kernel<<<dim3(BN * CIN / 256), 256, 0, stream>>>(x, xT);

  // 3. KNN
  knn_kernel<<<dim3(BN), 256, 0, stream>>>(pos, idx);

  // 4. hT = ls_w . x + ls_b
  gemmT_kernel<128, true><<<dim3(BN / 64, DIM / 64), 256, 0, stream>>>(xT, ls_wb, ls_b, hT, DIM);

  // 5. q,k,v projections
  gemmT_kernel<256, true ><<<dim3(BN / 64, DIM / 64), 256, 0, stream>>>(hT, qwb, qb, qT, DIM);
  gemmT_kernel<256, true ><<<dim3(BN / 64, DIM / 64), 256, 0, stream>>>(hT, kwb, kb, kT, DIM);
  gemmT_kernel<256, false><<<dim3(BN / 64, DIM / 64), 256, 0, stream>>>(hT, vwb, vb, vT, DIM);

  // 6. pe hidden (3->64, bn+relu)
  pe_hidden_kernel<<<dim3(BN), 64, 0, stream>>>(pos, idx, pw1, pe_scale, pe_shift, hidT);

  // 7. peT = pw2 . hid + pb2
  gemmT_kernel<64, true><<<dim3(CC / 64, DIM / 64), 256, 0, stream>>>(hidT, pw2b, pb2, peT, DIM);

  // 8. uT = q - k_gathered + pe
  u_kernel<<<dim3(CC), 256, 0, stream>>>(qT, kT, peT, idx, uT);

  // 9. fused attention MLP -> attn logits (aliases uT)
  attn_mlp_kernel<<<dim3(CC / 64), 256, 0, stream>>>(
      uT, aw1b, aw2b, at_scale, at_shift, ab2, attnT);

  // 10. softmax over K + aggregate
  softmax_agg_kernel<<<dim3(BN), 256, 0, stream>>>(attnT, peT, vT, idx, aggT);

  // 11. y = lw . agg + lb + identity
  final_kernel<<<dim3(BN / 64, CIN / 64), 256, 0, stream>>>(aggT, lwb, lb, x, (float*)d_out);
}

// Round 2
// 732.494 us; speedup vs baseline: 1.4615x; 1.4615x over previous
//
#include <hip/hip_runtime.h>
#include <hip/hip_bf16.h>
#include <math.h>

#define B_    4
#define CIN   128
#define NPTS  2048
#define DIM   256
#define PH    64
#define HIDN  1024
#define KNN_  16
#define BN    (B_*NPTS)      /* 8192  */
#define CC    (BN*KNN_)      /* 131072 */
#define EPS_  1e-5f

typedef __bf16 bf16;
typedef __bf16 bf16x8 __attribute__((ext_vector_type(8)));
typedef float  f32x4  __attribute__((ext_vector_type(4)));

// ---------------------------------------------------------------------------
// prep: fp32->bf16 weight conversion + batchnorm scale/shift folding
// ---------------------------------------------------------------------------
__global__ __launch_bounds__(256) void prep_kernel(
    const float* __restrict__ ls_w, const float* __restrict__ kw,
    const float* __restrict__ qw,   const float* __restrict__ vw,
    const float* __restrict__ pw2,  const float* __restrict__ aw1,
    const float* __restrict__ aw2,  const float* __restrict__ lw,
    const float* __restrict__ pb1,  const float* __restrict__ pg,
    const float* __restrict__ pbeta,const float* __restrict__ pmean,
    const float* __restrict__ pvar,
    const float* __restrict__ ab1,  const float* __restrict__ ag,
    const float* __restrict__ abeta,const float* __restrict__ amean,
    const float* __restrict__ avar,
    bf16* ls_wb, bf16* kwb, bf16* qwb, bf16* vwb,
    bf16* pw2b, bf16* aw1b, bf16* aw2b, bf16* lwb,
    float* pe_scale, float* pe_shift, float* at_scale, float* at_shift)
{
  long e = (long)blockIdx.x * 256 + threadIdx.x;
  if (e < 32768)  { ls_wb[e] = (bf16)ls_w[e]; return; } e -= 32768;
  if (e < 65536)  { kwb[e]   = (bf16)kw[e];   return; } e -= 65536;
  if (e < 65536)  { qwb[e]   = (bf16)qw[e];   return; } e -= 65536;
  if (e < 65536)  { vwb[e]   = (bf16)vw[e];   return; } e -= 65536;
  if (e < 16384)  { pw2b[e]  = (bf16)pw2[e];  return; } e -= 16384;
  if (e < 262144) { aw1b[e]  = (bf16)aw1[e];  return; } e -= 262144;
  if (e < 262144) { aw2b[e]  = (bf16)aw2[e];  return; } e -= 262144;
  if (e < 32768)  { lwb[e]   = (bf16)lw[e];   return; } e -= 32768;
  if (e < 64) {
    float sc = pg[e] * rsqrtf(pvar[e] + EPS_);
    pe_scale[e] = sc;
    pe_shift[e] = sc * pb1[e] + pbeta[e] - pmean[e] * sc;
    return;
  } e -= 64;
  if (e < 1024) {
    float sc = ag[e] * rsqrtf(avar[e] + EPS_);
    at_scale[e] = sc;
    at_shift[e] = sc * ab1[e] + abeta[e] - amean[e] * sc;
  }
}

// ---------------------------------------------------------------------------
// transpose x (B,CIN,N) fp32 -> xT (BN, CIN) bf16  (channel-last)
// ---------------------------------------------------------------------------
__global__ __launch_bounds__(256) void transpose_x_kernel(
    const float* __restrict__ x, bf16* __restrict__ xT)
{
  long e = (long)blockIdx.x * 256 + threadIdx.x;   // over BN*CIN
  int ch = (int)(e & (CIN - 1));
  long i = e >> 7;
  int n = (int)(i & (NPTS - 1));
  int b = (int)(i >> 11);
  xT[e] = (bf16)x[((long)b * CIN + ch) * NPTS + n];
}

// ---------------------------------------------------------------------------
// KNN: one block per query point; dist formula matches reference
// ---------------------------------------------------------------------------
__global__ __launch_bounds__(256) void knn_kernel(
    const float* __restrict__ pos, int* __restrict__ idx_out)
{
  __shared__ float px[NPTS], py[NPTS], pz[NPTS], dist[NPTS];
  __shared__ float sv[256];
  __shared__ int   si[256];
  int t = threadIdx.x;
  int bn = blockIdx.x;
  int b = bn >> 11;
  int i = bn & (NPTS - 1);
  const float* p = pos + (long)b * 3 * NPTS;
  for (int j = t; j < NPTS; j += 256) {
    px[j] = p[j]; py[j] = p[NPTS + j]; pz[j] = p[2 * NPTS + j];
  }
  __syncthreads();
  float qx = px[i], qy = py[i], qz = pz[i];
  float qs = qx * qx + qy * qy + qz * qz;
  for (int j = t; j < NPTS; j += 256) {
    float s2 = px[j] * px[j] + py[j] * py[j] + pz[j] * pz[j];
    float dt = qx * px[j] + qy * py[j] + qz * pz[j];
    dist[j] = qs + s2 - 2.f * dt;
  }
  __syncthreads();
  for (int r = 0; r < KNN_; ++r) {
    float best = 1e30f; int bi = NPTS;
    for (int j = t; j < NPTS; j += 256) {
      float d = dist[j];
      if (d < best) { best = d; bi = j; }
    }
    sv[t] = best; si[t] = bi;
    __syncthreads();
    for (int s = 128; s > 0; s >>= 1) {
      if (t < s) {
        if (sv[t + s] < sv[t] || (sv[t + s] == sv[t] && si[t + s] < si[t])) {
          sv[t] = sv[t + s]; si[t] = si[t + s];
        }
      }
      __syncthreads();
    }
    if (t == 0) {
      idx_out[(long)bn * KNN_ + r] = si[0];
      dist[si[0]] = 1e30f;
    }
    __syncthreads();
  }
}

// ---------------------------------------------------------------------------
// generic channel-last GEMM: out[i][o] = sum_k inT[i][k]*W[o][k] + bias[o]
// block tile 64x64, 4 waves each 32x32 (2x2 MFMA frags). KD multiple of 32.
// ---------------------------------------------------------------------------
template<int KD, bool OBF16>
__global__ __launch_bounds__(256) void gemmT_kernel(
    const bf16* __restrict__ inT, const bf16* __restrict__ Wb,
    const float* __restrict__ bias, void* __restrict__ outp, int O)
{
  const int tid = threadIdx.x;
  const int lane = tid & 63, wave = tid >> 6;
  const int row16 = lane & 15, grp = lane >> 4;
  const long i0 = (long)blockIdx.x * 64 + (wave & 1) * 32;
  const long o0 = (long)blockIdx.y * 64 + (wave >> 1) * 32;
  f32x4 acc[2][2] = {};
  const bf16* a0p = inT + (i0 + row16) * KD + grp * 8;
  const bf16* a1p = a0p + 16 * KD;
  const bf16* b0p = Wb + (o0 + row16) * KD + grp * 8;
  const bf16* b1p = b0p + 16 * KD;
#pragma unroll
  for (int ks = 0; ks < KD / 32; ++ks) {
    bf16x8 a0 = *(const bf16x8*)(a0p + ks * 32);
    bf16x8 a1 = *(const bf16x8*)(a1p + ks * 32);
    bf16x8 b0 = *(const bf16x8*)(b0p + ks * 32);
    bf16x8 b1 = *(const bf16x8*)(b1p + ks * 32);
    acc[0][0] = __builtin_amdgcn_mfma_f32_16x16x32_bf16(a0, b0, acc[0][0], 0, 0, 0);
    acc[0][1] = __builtin_amdgcn_mfma_f32_16x16x32_bf16(a0, b1, acc[0][1], 0, 0, 0);
    acc[1][0] = __builtin_amdgcn_mfma_f32_16x16x32_bf16(a1, b0, acc[1][0], 0, 0, 0);
    acc[1][1] = __builtin_amdgcn_mfma_f32_16x16x32_bf16(a1, b1, acc[1][1], 0, 0, 0);
  }
#pragma unroll
  for (int ot = 0; ot < 2; ++ot) {
    long o = o0 + ot * 16 + row16;
    float bv = bias[o];
#pragma unroll
    for (int it = 0; it < 2; ++it) {
#pragma unroll
      for (int r = 0; r < 4; ++r) {
        long i = i0 + it * 16 + grp * 4 + r;
        float v = acc[it][ot][r] + bv;
        if (OBF16) ((bf16*)outp)[i * O + o] = (bf16)v;
        else       ((float*)outp)[i * O + o] = v;
      }
    }
  }
}

// ---------------------------------------------------------------------------
// pe hidden layer: hidT[c][j] = relu(bn(pw1 . pos_rel)), c=(bn,k), j<64
// ---------------------------------------------------------------------------
__global__ __launch_bounds__(64) void pe_hidden_kernel(
    const float* __restrict__ pos, const int* __restrict__ idx,
    const float* __restrict__ pw1,
    const float* __restrict__ pe_scale, const float* __restrict__ pe_shift,
    bf16* __restrict__ hidT)
{
  int bn = blockIdx.x;
  int b = bn >> 11;
  int n = bn & (NPTS - 1);
  int j = threadIdx.x;
  const float* p = pos + (long)b * 3 * NPTS;
  float qx = p[n], qy = p[NPTS + n], qz = p[2 * NPTS + n];
  float w0 = pw1[j * 3], w1 = pw1[j * 3 + 1], w2 = pw1[j * 3 + 2];
  float sc = pe_scale[j], sh = pe_shift[j];
#pragma unroll
  for (int k = 0; k < KNN_; ++k) {
    int nb = idx[(long)bn * KNN_ + k];
    float rx = qx - p[nb], ry = qy - p[NPTS + nb], rz = qz - p[2 * NPTS + nb];
    float v = w0 * rx + w1 * ry + w2 * rz;
    v = sc * v + sh;
    v = v > 0.f ? v : 0.f;
    hidT[((long)bn * KNN_ + k) * PH + j] = (bf16)v;
  }
}

// ---------------------------------------------------------------------------
// uT[c][ch] = query[bn][ch] - key[(b,idx[c])][ch] + pe[c][ch]
// ---------------------------------------------------------------------------
__global__ __launch_bounds__(256) void u_kernel(
    const bf16* __restrict__ qT, const bf16* __restrict__ kT,
    const bf16* __restrict__ peT, const int* __restrict__ idx,
    bf16* __restrict__ uT)
{
  long c = blockIdx.x;              // one column per block (256 ch threads)
  int ch = threadIdx.x;
  long bn = c >> 4;
  int b = (int)(bn >> 11);
  int nb = idx[c];
  long e = c * DIM + ch;
  float v = (float)qT[bn * DIM + ch] - (float)kT[((long)b * NPTS + nb) * DIM + ch]
          + (float)peT[e];
  uT[e] = (bf16)v;
}

// ---------------------------------------------------------------------------
// fused attention MLP v2: attnT = ab2 + aw2 . relu(bn(aw1 . uT))
//
// Block = 64 columns, 4 waves, HID chunked at 128 (8 chunks, 16 barriers).
//  - u tile (64x256) staged ONCE into padded LDS (stride 264, 2-way-free reads)
//  - GEMM1 split by HIDDEN slab per wave (32 hid each) -> no redundant aw1
//    loads across waves; A-frags from LDS.
//  - t tile (64x128, stride 136, 16B aligned) -> GEMM2 A-frags 2-way-free.
//  - GEMM2 split by OUTPUT slab per wave (64 outs each); acc2 persistent.
// attnT may alias uT: u fully staged to LDS before any store.
// ---------------------------------------------------------------------------
__global__ __launch_bounds__(256, 2) void attn_mlp_kernel(
    const bf16* __restrict__ uT, const bf16* __restrict__ aw1b,
    const bf16* __restrict__ aw2b,
    const float* __restrict__ at_scale, const float* __restrict__ at_shift,
    const float* __restrict__ ab2, bf16* __restrict__ attnT)
{
  __shared__ __align__(16) bf16 u_lds[64][264];   // 256 + 8 pad
  __shared__ __align__(16) bf16 t_lds[64][136];   // 128 + 8 pad
  const int tid = threadIdx.x;
  const int lane = tid & 63, wave = tid >> 6;
  const int row16 = lane & 15, grp = lane >> 4;
  const long c0 = (long)blockIdx.x * 64;

  // ---- stage u tile: 64 rows x 256 ch = 2048 x 16B chunks, 8 iters ----
#pragma unroll
  for (int it = 0; it < 8; ++it) {
    int id = it * 256 + tid;
    int col = id >> 5, ch16 = id & 31;
    bf16x8 v = *(const bf16x8*)(uT + (c0 + col) * DIM + ch16 * 8);
    *(bf16x8*)&u_lds[col][ch16 * 8] = v;
  }
  __syncthreads();

  const int hs = wave * 32;           // GEMM1 hid slab (within 128-chunk)
  const int os = wave * 64;           // GEMM2 out slab
  f32x4 acc2[4][4] = {};

  for (int jc = 0; jc < 8; ++jc) {
    const int hg = jc * 128 + hs;     // global hid base of this wave's slab
    // ---- GEMM1: t[0..64][hs..hs+32] = relu(bn(aw1 . u)) ----
    f32x4 acc1[4][2] = {};
#pragma unroll
    for (int ks = 0; ks < 8; ++ks) {
      bf16x8 a[4], b[2];
#pragma unroll
      for (int ct = 0; ct < 4; ++ct)
        a[ct] = *(const bf16x8*)(&u_lds[ct * 16 + row16][ks * 32 + grp * 8]);
#pragma unroll
      for (int ht = 0; ht < 2; ++ht)
        b[ht] = *(const bf16x8*)(aw1b + (long)(hg + ht * 16 + row16) * DIM + ks * 32 + grp * 8);
#pragma unroll
      for (int ct = 0; ct < 4; ++ct)
#pragma unroll
        for (int ht = 0; ht < 2; ++ht)
          acc1[ct][ht] = __builtin_amdgcn_mfma_f32_16x16x32_bf16(a[ct], b[ht], acc1[ct][ht], 0, 0, 0);
    }
#pragma unroll
    for (int ht = 0; ht < 2; ++ht) {
      int jg = hg + ht * 16 + row16;
      float sc = at_scale[jg], sh = at_shift[jg];
#pragma unroll
      for (int ct = 0; ct < 4; ++ct) {
#pragma unroll
        for (int r = 0; r < 4; ++r) {
          float v = sc * acc1[ct][ht][r] + sh;
          v = v > 0.f ? v : 0.f;
          t_lds[ct * 16 + grp * 4 + r][hs + ht * 16 + row16] = (bf16)v;
        }
      }
    }
    __syncthreads();
    // ---- GEMM2: acc2[c][o] += t[c][j] * aw2[o][j], K = 128 chunk ----
#pragma unroll
    for (int ks2 = 0; ks2 < 4; ++ks2) {
      bf16x8 a2[4], b2[4];
#pragma unroll
      for (int ct = 0; ct < 4; ++ct)
        a2[ct] = *(const bf16x8*)(&t_lds[ct * 16 + row16][ks2 * 32 + grp * 8]);
#pragma unroll
      for (int ot = 0; ot < 4; ++ot)
        b2[ot] = *(const bf16x8*)(aw2b + (long)(os + ot * 16 + row16) * HIDN + jc * 128 + ks2 * 32 + grp * 8);
#pragma unroll
      for (int ct = 0; ct < 4; ++ct)
#pragma unroll
        for (int ot = 0; ot < 4; ++ot)
          acc2[ct][ot] = __builtin_amdgcn_mfma_f32_16x16x32_bf16(a2[ct], b2[ot], acc2[ct][ot], 0, 0, 0);
    }
    __syncthreads();
  }
  // epilogue: + ab2, store bf16
#pragma unroll
  for (int ot = 0; ot < 4; ++ot) {
    int o = os + ot * 16 + row16;
    float bv = ab2[o];
#pragma unroll
    for (int ct = 0; ct < 4; ++ct) {
#pragma unroll
      for (int r = 0; r < 4; ++r) {
        long c = c0 + ct * 16 + grp * 4 + r;
        attnT[c * DIM + o] = (bf16)(acc2[ct][ot][r] + bv);
      }
    }
  }
}

// ---------------------------------------------------------------------------
// softmax over K + aggregation: aggT[bn][o] = sum_k softmax(attn)[k]*(v+pe)
// ---------------------------------------------------------------------------
__global__ __launch_bounds__(256) void softmax_agg_kernel(
    const bf16* __restrict__ attnT, const bf16* __restrict__ peT,
    const float* __restrict__ vT, const int* __restrict__ idx,
    bf16* __restrict__ aggT)
{
  long bn = blockIdx.x;
  int b = (int)(bn >> 11);
  int o = threadIdx.x;
  float l[KNN_];
  float m = -1e30f;
#pragma unroll
  for (int k = 0; k < KNN_; ++k) {
    l[k] = (float)attnT[(bn * KNN_ + k) * DIM + o];
    m = fmaxf(m, l[k]);
  }
  float s = 0.f;
#pragma unroll
  for (int k = 0; k < KNN_; ++k) { l[k] = expf(l[k] - m); s += l[k]; }
  float inv = 1.f / s;
  float agg = 0.f;
#pragma unroll
  for (int k = 0; k < KNN_; ++k) {
    int nb = idx[bn * KNN_ + k];
    float vg = vT[((long)b * NPTS + nb) * DIM + o] + (float)peT[(bn * KNN_ + k) * DIM + o];
    agg += l[k] * inv * vg;
  }
  aggT[bn * DIM + o] = (bf16)agg;
}

// ---------------------------------------------------------------------------
// final: out[b][o][n] = lw . agg + lb + identity  (fp32, channel-major out)
// ---------------------------------------------------------------------------
__global__ __launch_bounds__(256) void final_kernel(
    const bf16* __restrict__ aggT, const bf16* __restrict__ lwb,
    const float* __restrict__ lb, const float* __restrict__ x,
    float* __restrict__ out)
{
  const int tid = threadIdx.x;
  const int lane = tid & 63, wave = tid >> 6;
  const int row16 = lane & 15, grp = lane >> 4;
  const long i0 = (long)blockIdx.x * 64 + (wave & 1) * 32;
  const int o0 = blockIdx.y * 64 + (wave >> 1) * 32;
  f32x4 acc[2][2] = {};
  const bf16* a0p = aggT + (i0 + row16) * DIM + grp * 8;
  const bf16* a1p = a0p + 16 * DIM;
  const bf16* b0p = lwb + (long)(o0 + row16) * DIM + grp * 8;
  const bf16* b1p = b0p + 16 * DIM;
#pragma unroll
  for (int ks = 0; ks < 8; ++ks) {
    bf16x8 a0 = *(const bf16x8*)(a0p + ks * 32);
    bf16x8 a1 = *(const bf16x8*)(a1p + ks * 32);
    bf16x8 b0 = *(const bf16x8*)(b0p + ks * 32);
    bf16x8 b1 = *(const bf16x8*)(b1p + ks * 32);
    acc[0][0] = __builtin_amdgcn_mfma_f32_16x16x32_bf16(a0, b0, acc[0][0], 0, 0, 0);
    acc[0][1] = __builtin_amdgcn_mfma_f32_16x16x32_bf16(a0, b1, acc[0][1], 0, 0, 0);
    acc[1][0] = __builtin_amdgcn_mfma_f32_16x16x32_bf16(a1, b0, acc[1][0], 0, 0, 0);
    acc[1][1] = __builtin_amdgcn_mfma_f32_16x16x32_bf16(a1, b1, acc[1][1], 0, 0, 0);
  }
#pragma unroll
  for (int ot = 0; ot < 2; ++ot) {
    int o = o0 + ot * 16 + row16;
    float bv = lb[o];
#pragma unroll
    for (int it = 0; it < 2; ++it) {
#pragma unroll
      for (int r = 0; r < 4; ++r) {
        long i = i0 + it * 16 + grp * 4 + r;
        int b = (int)(i >> 11);
        int n = (int)(i & (NPTS - 1));
        long off = ((long)b * CIN + o) * NPTS + n;
        out[off] = acc[it][ot][r] + bv + x[off];
      }
    }
  }
}

// ---------------------------------------------------------------------------
extern "C" void kernel_launch(void* const* d_in, const int* in_sizes, int n_in,
                              void* d_out, int out_size, void* d_ws, size_t ws_size,
                              hipStream_t stream)
{
  const float* x     = (const float*)d_in[0];
  const float* pos   = (const float*)d_in[1];
  const float* ls_w  = (const float*)d_in[2];
  const float* ls_b  = (const float*)d_in[3];
  const float* kw    = (const float*)d_in[4];
  const float* kb    = (const float*)d_in[5];
  const float* qw    = (const float*)d_in[6];
  const float* qb    = (const float*)d_in[7];
  const float* vw    = (const float*)d_in[8];
  const float* vb    = (const float*)d_in[9];
  const float* pw1   = (const float*)d_in[10];
  const float* pb1   = (const float*)d_in[11];
  const float* pg    = (const float*)d_in[12];
  const float* pbeta = (const float*)d_in[13];
  const float* pmean = (const float*)d_in[14];
  const float* pvar  = (const float*)d_in[15];
  const float* pw2   = (const float*)d_in[16];
  const float* pb2   = (const float*)d_in[17];
  const float* aw1   = (const float*)d_in[18];
  const float* ab1   = (const float*)d_in[19];
  const float* ag    = (const float*)d_in[20];
  const float* abeta = (const float*)d_in[21];
  const float* amean = (const float*)d_in[22];
  const float* avar  = (const float*)d_in[23];
  const float* aw2   = (const float*)d_in[24];
  const float* ab2   = (const float*)d_in[25];
  const float* lw    = (const float*)d_in[26];
  const float* lb    = (const float*)d_in[27];

  char* ws = (char*)d_ws;
  size_t off = 0;
  auto alloc = [&](size_t bytes) -> void* {
    void* p = ws + off;
    off = (off + bytes + 255) & ~(size_t)255;
    return p;
  };

  bf16* ls_wb = (bf16*)alloc(32768 * 2);
  bf16* kwb   = (bf16*)alloc(65536 * 2);
  bf16* qwb   = (bf16*)alloc(65536 * 2);
  bf16* vwb   = (bf16*)alloc(65536 * 2);
  bf16* pw2b  = (bf16*)alloc(16384 * 2);
  bf16* aw1b  = (bf16*)alloc(262144 * 2);
  bf16* aw2b  = (bf16*)alloc(262144 * 2);
  bf16* lwb   = (bf16*)alloc(32768 * 2);
  float* pe_scale = (float*)alloc(64 * 4);
  float* pe_shift = (float*)alloc(64 * 4);
  float* at_scale = (float*)alloc(1024 * 4);
  float* at_shift = (float*)alloc(1024 * 4);
  int*  idx  = (int*)alloc((size_t)CC * 4);
  bf16* xT   = (bf16*)alloc((size_t)BN * CIN * 2);
  bf16* hT   = (bf16*)alloc((size_t)BN * DIM * 2);
  bf16* qT   = (bf16*)alloc((size_t)BN * DIM * 2);
  bf16* kT   = (bf16*)alloc((size_t)BN * DIM * 2);
  float* vT  = (float*)alloc((size_t)BN * DIM * 4);
  bf16* hidT = (bf16*)alloc((size_t)CC * PH * 2);
  bf16* peT  = (bf16*)alloc((size_t)CC * DIM * 2);
  bf16* uT   = (bf16*)alloc((size_t)CC * DIM * 2);
  bf16* attnT = uT;  // alias: attn_mlp stages u to LDS before storing
  bf16* aggT = (bf16*)alloc((size_t)BN * DIM * 2);

  // 1. prep (converts + bn folding): 802816 + 64 + 1024 = 803904 elems
  prep_kernel<<<dim3((803904 + 255) / 256), 256, 0, stream>>>(
      ls_w, kw, qw, vw, pw2, aw1, aw2, lw,
      pb1, pg, pbeta, pmean, pvar, ab1, ag, abeta, amean, avar,
      ls_wb, kwb, qwb, vwb, pw2b, aw1b, aw2b, lwb,
      pe_scale, pe_shift, at_scale, at_shift);

  // 2. transpose x -> xT (channel-last bf16)
  transpose_x_kernel<<<dim3(BN * CIN / 256), 256, 0, stream>>>(x, xT);

  // 3. KNN
  knn_kernel<<<dim3(BN), 256, 0, stream>>>(pos, idx);

  // 4. hT = ls_w . x + ls_b
  gemmT_kernel<128, true><<<dim3(BN / 64, DIM / 64), 256, 0, stream>>>(xT, ls_wb, ls_b, hT, DIM);

  // 5. q,k,v projections
  gemmT_kernel<256, true ><<<dim3(BN / 64, DIM / 64), 256, 0, stream>>>(hT, qwb, qb, qT, DIM);
  gemmT_kernel<256, true ><<<dim3(BN / 64, DIM / 64), 256, 0, stream>>>(hT, kwb, kb, kT, DIM);
  gemmT_kernel<256, false><<<dim3(BN / 64, DIM / 64), 256, 0, stream>>>(hT, vwb, vb, vT, DIM);

  // 6. pe hidden (3->64, bn+relu)
  pe_hidden_kernel<<<dim3(BN), 64, 0, stream>>>(pos, idx, pw1, pe_scale, pe_shift, hidT);

  // 7. peT = pw2 . hid + pb2
  gemmT_kernel<64, true><<<dim3(CC / 64, DIM / 64), 256, 0, stream>>>(hidT, pw2b, pb2, peT, DIM);

  // 8. uT = q - k_gathered + pe
  u_kernel<<<dim3(CC), 256, 0, stream>>>(qT, kT, peT, idx, uT);

  // 9. fused attention MLP v2 -> attn logits (aliases uT)
  attn_mlp_kernel<<<dim3(CC / 64), 256, 0, stream>>>(
      uT, aw1b, aw2b, at_scale, at_shift, ab2, attnT);

  // 10. softmax over K + aggregate
  softmax_agg_kernel<<<dim3(BN), 256, 0, stream>>>(attnT, peT, vT, idx, aggT);

  // 11. y = lw . agg + lb + identity
  final_kernel<<<dim3(BN / 64, CIN / 64), 256, 0, stream>>>(aggT, lwb, lb, x, (float*)d_out);
}

// Round 3
// 513.924 us; speedup vs baseline: 2.0830x; 1.4253x over previous
//
#include <hip/hip_runtime.h>
#include <hip/hip_bf16.h>
#include <math.h>

#define B_    4
#define CIN   128
#define NPTS  2048
#define DIM   256
#define PH    64
#define HIDN  1024
#define KNN_  16
#define BN    (B_*NPTS)      /* 8192  */
#define CC    (BN*KNN_)      /* 131072 */
#define EPS_  1e-5f

typedef __bf16 bf16;
typedef __bf16 bf16x8 __attribute__((ext_vector_type(8)));
typedef __bf16 bf16x4 __attribute__((ext_vector_type(4)));
typedef float  f32x4  __attribute__((ext_vector_type(4)));

// ---------------------------------------------------------------------------
// prep: fp32->bf16 weight conversion + batchnorm scale/shift folding
// ---------------------------------------------------------------------------
__global__ __launch_bounds__(256) void prep_kernel(
    const float* __restrict__ ls_w, const float* __restrict__ kw,
    const float* __restrict__ qw,   const float* __restrict__ vw,
    const float* __restrict__ pw2,  const float* __restrict__ aw1,
    const float* __restrict__ aw2,  const float* __restrict__ lw,
    const float* __restrict__ pb1,  const float* __restrict__ pg,
    const float* __restrict__ pbeta,const float* __restrict__ pmean,
    const float* __restrict__ pvar,
    const float* __restrict__ ab1,  const float* __restrict__ ag,
    const float* __restrict__ abeta,const float* __restrict__ amean,
    const float* __restrict__ avar,
    bf16* ls_wb, bf16* kwb, bf16* qwb, bf16* vwb,
    bf16* pw2b, bf16* aw1b, bf16* aw2b, bf16* lwb,
    float* pe_scale, float* pe_shift, float* at_scale, float* at_shift)
{
  long e = (long)blockIdx.x * 256 + threadIdx.x;
  if (e < 32768)  { ls_wb[e] = (bf16)ls_w[e]; return; } e -= 32768;
  if (e < 65536)  { kwb[e]   = (bf16)kw[e];   return; } e -= 65536;
  if (e < 65536)  { qwb[e]   = (bf16)qw[e];   return; } e -= 65536;
  if (e < 65536)  { vwb[e]   = (bf16)vw[e];   return; } e -= 65536;
  if (e < 16384)  { pw2b[e]  = (bf16)pw2[e];  return; } e -= 16384;
  if (e < 262144) { aw1b[e]  = (bf16)aw1[e];  return; } e -= 262144;
  if (e < 262144) { aw2b[e]  = (bf16)aw2[e];  return; } e -= 262144;
  if (e < 32768)  { lwb[e]   = (bf16)lw[e];   return; } e -= 32768;
  if (e < 64) {
    float sc = pg[e] * rsqrtf(pvar[e] + EPS_);
    pe_scale[e] = sc;
    pe_shift[e] = sc * pb1[e] + pbeta[e] - pmean[e] * sc;   // includes pb1
    return;
  } e -= 64;
  if (e < 1024) {
    float sc = ag[e] * rsqrtf(avar[e] + EPS_);
    at_scale[e] = sc;
    at_shift[e] = sc * ab1[e] + abeta[e] - amean[e] * sc;   // includes ab1
  }
}

// ---------------------------------------------------------------------------
// transpose x (B,CIN,N) fp32 -> xT (BN, CIN) bf16  (channel-last)
// ---------------------------------------------------------------------------
__global__ __launch_bounds__(256) void transpose_x_kernel(
    const float* __restrict__ x, bf16* __restrict__ xT)
{
  long e = (long)blockIdx.x * 256 + threadIdx.x;   // over BN*CIN
  int ch = (int)(e & (CIN - 1));
  long i = e >> 7;
  int n = (int)(i & (NPTS - 1));
  int b = (int)(i >> 11);
  xT[e] = (bf16)x[((long)b * CIN + ch) * NPTS + n];
}

// ---------------------------------------------------------------------------
// KNN v2: one WAVE per query point (4 queries/block). Distances live in
// 32 registers/lane (idx implicit: pt = j*64 + lane); 16 rounds of
// in-register argmin + shfl butterfly (value, lowest-index tiebreak).
// ---------------------------------------------------------------------------
__global__ __launch_bounds__(256) void knn_kernel(
    const float* __restrict__ pos, int* __restrict__ idx_out)
{
  __shared__ float px[NPTS], py[NPTS], pz[NPTS];
  const int tid = threadIdx.x;
  const int lane = tid & 63, wave = tid >> 6;
  const int q = blockIdx.x * 4 + wave;       // global query id
  const int b = q >> 11;
  const int n = q & (NPTS - 1);
  const float* p = pos + (long)b * 3 * NPTS;
  for (int j = tid; j < NPTS; j += 256) {
    px[j] = p[j]; py[j] = p[NPTS + j]; pz[j] = p[2 * NPTS + j];
  }
  __syncthreads();
  float qx = px[n], qy = py[n], qz = pz[n];
  float qs = qx * qx + qy * qy + qz * qz;
  float d[32];
#pragma unroll
  for (int j = 0; j < 32; ++j) {
    int pt = j * 64 + lane;
    float x = px[pt], y = py[pt], z = pz[pt];
    float s2 = x * x + y * y + z * z;
    float dt = qx * x + qy * y + qz * z;
    d[j] = qs + s2 - 2.f * dt;
  }
  for (int r = 0; r < KNN_; ++r) {
    float bv = 1e30f; int bj = 0;
#pragma unroll
    for (int j = 0; j < 32; ++j)
      if (d[j] < bv) { bv = d[j]; bj = j; }
    int bi = bj * 64 + lane;
#pragma unroll
    for (int off = 32; off >= 1; off >>= 1) {
      float ov = __shfl_xor(bv, off);
      int   oi = __shfl_xor(bi, off);
      if (ov < bv || (ov == bv && oi < bi)) { bv = ov; bi = oi; }
    }
    if (lane == 0) idx_out[(long)q * KNN_ + r] = bi;
#pragma unroll
    for (int j = 0; j < 32; ++j)
      if (bi == j * 64 + lane) d[j] = 1e30f;
  }
}

// ---------------------------------------------------------------------------
// generic channel-last GEMM: out[i][o] = sum_k inT[i][k]*W[o][k] + bias[o]
// block tile 64x64, 4 waves each 32x32 (2x2 MFMA frags). KD multiple of 32.
// ---------------------------------------------------------------------------
template<int KD, bool OBF16>
__global__ __launch_bounds__(256) void gemmT_kernel(
    const bf16* __restrict__ inT, const bf16* __restrict__ Wb,
    const float* __restrict__ bias, void* __restrict__ outp, int O)
{
  const int tid = threadIdx.x;
  const int lane = tid & 63, wave = tid >> 6;
  const int row16 = lane & 15, grp = lane >> 4;
  const long i0 = (long)blockIdx.x * 64 + (wave & 1) * 32;
  const long o0 = (long)blockIdx.y * 64 + (wave >> 1) * 32;
  f32x4 acc[2][2] = {};
  const bf16* a0p = inT + (i0 + row16) * KD + grp * 8;
  const bf16* a1p = a0p + 16 * KD;
  const bf16* b0p = Wb + (o0 + row16) * KD + grp * 8;
  const bf16* b1p = b0p + 16 * KD;
#pragma unroll
  for (int ks = 0; ks < KD / 32; ++ks) {
    bf16x8 a0 = *(const bf16x8*)(a0p + ks * 32);
    bf16x8 a1 = *(const bf16x8*)(a1p + ks * 32);
    bf16x8 b0 = *(const bf16x8*)(b0p + ks * 32);
    bf16x8 b1 = *(const bf16x8*)(b1p + ks * 32);
    acc[0][0] = __builtin_amdgcn_mfma_f32_16x16x32_bf16(a0, b0, acc[0][0], 0, 0, 0);
    acc[0][1] = __builtin_amdgcn_mfma_f32_16x16x32_bf16(a0, b1, acc[0][1], 0, 0, 0);
    acc[1][0] = __builtin_amdgcn_mfma_f32_16x16x32_bf16(a1, b0, acc[1][0], 0, 0, 0);
    acc[1][1] = __builtin_amdgcn_mfma_f32_16x16x32_bf16(a1, b1, acc[1][1], 0, 0, 0);
  }
#pragma unroll
  for (int ot = 0; ot < 2; ++ot) {
    long o = o0 + ot * 16 + row16;
    float bv = bias[o];
#pragma unroll
    for (int it = 0; it < 2; ++it) {
#pragma unroll
      for (int r = 0; r < 4; ++r) {
        long i = i0 + it * 16 + grp * 4 + r;
        float v = acc[it][ot][r] + bv;
        if (OBF16) ((bf16*)outp)[i * O + o] = (bf16)v;
        else       ((float*)outp)[i * O + o] = v;
      }
    }
  }
}

// ---------------------------------------------------------------------------
// FUSED attention kernel: per 64-column block (= 4 points x 16 neighbors):
//   1. gather k rows -> u_lds; rel/idx -> LDS
//   2. hid = relu(bn(pw1 . rel)) -> hid_lds (overlays t_lds)
//   3. pe GEMM (hid x pw2) -> regs; u_lds = q - k + pe (RMW); pe kept bf16
//   4. MLP jc-loop: GEMM1 (A=aw1 -> b64 conflict-free t-stores), GEMM2 -> acc2
//   5. softmax over K via shfl; agg = sum p*(v_gather + pe); write aggT only
// ---------------------------------------------------------------------------
__global__ __launch_bounds__(256, 2) void attn_fused_kernel(
    const bf16* __restrict__ qT, const bf16* __restrict__ kT,
    const bf16* __restrict__ vTb, const float* __restrict__ pos,
    const int* __restrict__ idx, const float* __restrict__ pw1,
    const float* __restrict__ pe_scale, const float* __restrict__ pe_shift,
    const bf16* __restrict__ pw2b, const float* __restrict__ pb2,
    const bf16* __restrict__ aw1b, const bf16* __restrict__ aw2b,
    const float* __restrict__ at_scale, const float* __restrict__ at_shift,
    const float* __restrict__ ab2, bf16* __restrict__ aggT)
{
  __shared__ __align__(16) bf16 u_lds[64][264];   // k-gather, then u
  __shared__ __align__(16) bf16 tbuf[64 * 136];   // t tile / hid overlay
  __shared__ float rel_lds[64][4];
  __shared__ int   idx_lds[64];
  bf16 (*t_lds)[136]  = (bf16(*)[136])tbuf;
  bf16 (*hid_lds)[72] = (bf16(*)[72])tbuf;        // 9216 B <= 17408 B

  const int tid = threadIdx.x;
  const int lane = tid & 63, wave = tid >> 6;
  const int row16 = lane & 15, grp = lane >> 4;
  const long c0 = (long)blockIdx.x * 64;
  const int bn0 = blockIdx.x * 4;
  const int b = bn0 >> 11;
  const float* pB = pos + (long)b * 3 * NPTS;
  const int os = wave * 64;             // this wave's output-channel slab

  // ---- stage idx + pos_rel + k rows ----
  if (tid < 64) {
    int nb = idx[c0 + tid];
    idx_lds[tid] = nb;
    int n = (bn0 + (tid >> 4)) & (NPTS - 1);
    rel_lds[tid][0] = pB[n] - pB[nb];
    rel_lds[tid][1] = pB[NPTS + n] - pB[NPTS + nb];
    rel_lds[tid][2] = pB[2 * NPTS + n] - pB[2 * NPTS + nb];
  }
#pragma unroll
  for (int it = 0; it < 8; ++it) {
    int id = it * 256 + tid;
    int col = id >> 5, ch16 = id & 31;
    int nb = idx[c0 + col];
    *(bf16x8*)&u_lds[col][ch16 * 8] =
        *(const bf16x8*)(kT + ((long)b * NPTS + nb) * DIM + ch16 * 8);
  }
  __syncthreads();

  // ---- hid = relu(bn(pw1 . rel)) ----
  {
    int c = tid & 63, jq = tid >> 6;
    float rx = rel_lds[c][0], ry = rel_lds[c][1], rz = rel_lds[c][2];
#pragma unroll
    for (int jj = 0; jj < 16; ++jj) {
      int j = jq * 16 + jj;
      float v = pw1[j * 3] * rx + pw1[j * 3 + 1] * ry + pw1[j * 3 + 2] * rz;
      v = pe_scale[j] * v + pe_shift[j];
      hid_lds[c][j] = (bf16)fmaxf(v, 0.f);
    }
  }
  __syncthreads();

  // ---- pe GEMM: accpe[ct][ot] holds pe[c=ct*16+grp*4+r][o=os+ot*16+row16] ----
  f32x4 accpe[4][4] = {};
#pragma unroll
  for (int ks = 0; ks < 2; ++ks) {
    bf16x8 ah[4];
#pragma unroll
    for (int ct = 0; ct < 4; ++ct)
      ah[ct] = *(const bf16x8*)&hid_lds[ct * 16 + row16][ks * 32 + grp * 8];
#pragma unroll
    for (int ot = 0; ot < 4; ++ot) {
      bf16x8 bw = *(const bf16x8*)(pw2b + (long)(os + ot * 16 + row16) * PH + ks * 32 + grp * 8);
#pragma unroll
      for (int ct = 0; ct < 4; ++ct)
        accpe[ct][ot] = __builtin_amdgcn_mfma_f32_16x16x32_bf16(ah[ct], bw, accpe[ct][ot], 0, 0, 0);
    }
  }

  // ---- u = q - k + pe (RMW on this wave's o-slab); keep pe as bf16 ----
  bf16x4 pe_bf[4][4];
#pragma unroll
  for (int ot = 0; ot < 4; ++ot) {
    int o = os + ot * 16 + row16;
    float pb2v = pb2[o];
#pragma unroll
    for (int ct = 0; ct < 4; ++ct) {
      float qv = (float)qT[(long)(bn0 + ct) * DIM + o];
#pragma unroll
      for (int r = 0; r < 4; ++r) {
        int c = ct * 16 + grp * 4 + r;
        float pev = accpe[ct][ot][r] + pb2v;
        float kv = (float)u_lds[c][o];
        u_lds[c][o] = (bf16)(qv - kv + pev);
        pe_bf[ct][ot][r] = (bf16)pev;
      }
    }
  }
  __syncthreads();

  // ---- MLP: attn = ab2 + aw2 . relu(bn(aw1 . u)), HID chunked at 128 ----
  const int hs = wave * 32;             // this wave's 32-hid slab in chunk
  f32x4 acc2[4][4] = {};
  for (int jc = 0; jc < 8; ++jc) {
    const int hg = jc * 128 + hs;
    // GEMM1 (A=aw1 rows=j, B=u cols=c): D row=j, col=c
    f32x4 acc1[4][2] = {};
#pragma unroll
    for (int ks = 0; ks < 8; ++ks) {
      bf16x8 bu[4], aw[2];
#pragma unroll
      for (int ct = 0; ct < 4; ++ct)
        bu[ct] = *(const bf16x8*)&u_lds[ct * 16 + row16][ks * 32 + grp * 8];
#pragma unroll
      for (int jt = 0; jt < 2; ++jt)
        aw[jt] = *(const bf16x8*)(aw1b + (long)(hg + jt * 16 + row16) * DIM + ks * 32 + grp * 8);
#pragma unroll
      for (int ct = 0; ct < 4; ++ct)
#pragma unroll
        for (int jt = 0; jt < 2; ++jt)
          acc1[ct][jt] = __builtin_amdgcn_mfma_f32_16x16x32_bf16(aw[jt], bu[ct], acc1[ct][jt], 0, 0, 0);
    }
    // epilogue: lane holds t[c=ct*16+row16][j=hg+jt*16+grp*4+r] -> b64 stores
#pragma unroll
    for (int jt = 0; jt < 2; ++jt) {
      f32x4 sc4 = *(const f32x4*)&at_scale[hg + jt * 16 + grp * 4];
      f32x4 sh4 = *(const f32x4*)&at_shift[hg + jt * 16 + grp * 4];
#pragma unroll
      for (int ct = 0; ct < 4; ++ct) {
        bf16x4 pk;
#pragma unroll
        for (int r = 0; r < 4; ++r) {
          float v = sc4[r] * acc1[ct][jt][r] + sh4[r];
          pk[r] = (bf16)fmaxf(v, 0.f);
        }
        *(bf16x4*)&t_lds[ct * 16 + row16][hs + jt * 16 + grp * 4] = pk;
      }
    }
    __syncthreads();
    // GEMM2: acc2[c][o] += t[c][j] * aw2[o][j]
#pragma unroll
    for (int ks2 = 0; ks2 < 4; ++ks2) {
      bf16x8 a2[4], b2;
#pragma unroll
      for (int ct = 0; ct < 4; ++ct)
        a2[ct] = *(const bf16x8*)&t_lds[ct * 16 + row16][ks2 * 32 + grp * 8];
#pragma unroll
      for (int ot = 0; ot < 4; ++ot) {
        b2 = *(const bf16x8*)(aw2b + (long)(os + ot * 16 + row16) * HIDN + jc * 128 + ks2 * 32 + grp * 8);
#pragma unroll
        for (int ct = 0; ct < 4; ++ct)
          acc2[ct][ot] = __builtin_amdgcn_mfma_f32_16x16x32_bf16(a2[ct], b2, acc2[ct][ot], 0, 0, 0);
      }
    }
    __syncthreads();
  }

  // ---- softmax over K (k = grp*4+r across grp-lanes) + aggregation ----
#pragma unroll
  for (int ct = 0; ct < 4; ++ct) {
#pragma unroll
    for (int ot = 0; ot < 4; ++ot) {
      int o = os + ot * 16 + row16;
      float ab = ab2[o];
      float l[4];
      float m = -1e30f;
#pragma unroll
      for (int r = 0; r < 4; ++r) {
        l[r] = acc2[ct][ot][r] + ab;
        m = fmaxf(m, l[r]);
      }
      m = fmaxf(m, __shfl_xor(m, 16));
      m = fmaxf(m, __shfl_xor(m, 32));
      float s = 0.f;
#pragma unroll
      for (int r = 0; r < 4; ++r) { l[r] = expf(l[r] - m); s += l[r]; }
      s += __shfl_xor(s, 16);
      s += __shfl_xor(s, 32);
      float inv = 1.f / s;
      float agg = 0.f;
#pragma unroll
      for (int r = 0; r < 4; ++r) {
        int c = ct * 16 + grp * 4 + r;
        int nb = idx_lds[c];
        float vv = (float)vTb[((long)b * NPTS + nb) * DIM + o];
        agg += l[r] * (vv + (float)pe_bf[ct][ot][r]);
      }
      agg *= inv;
      agg += __shfl_xor(agg, 16);
      agg += __shfl_xor(agg, 32);
      if (grp == 0) aggT[(long)(bn0 + ct) * DIM + o] = (bf16)agg;
    }
  }
}

// ---------------------------------------------------------------------------
// final: out[b][o][n] = lw . agg + lb + identity  (fp32, channel-major out)
// ---------------------------------------------------------------------------
__global__ __launch_bounds__(256) void final_kernel(
    const bf16* __restrict__ aggT, const bf16* __restrict__ lwb,
    const float* __restrict__ lb, const float* __restrict__ x,
    float* __restrict__ out)
{
  const int tid = threadIdx.x;
  const int lane = tid & 63, wave = tid >> 6;
  const int row16 = lane & 15, grp = lane >> 4;
  const long i0 = (long)blockIdx.x * 64 + (wave & 1) * 32;
  const int o0 = blockIdx.y * 64 + (wave >> 1) * 32;
  f32x4 acc[2][2] = {};
  const bf16* a0p = aggT + (i0 + row16) * DIM + grp * 8;
  const bf16* a1p = a0p + 16 * DIM;
  const bf16* b0p = lwb + (long)(o0 + row16) * DIM + grp * 8;
  const bf16* b1p = b0p + 16 * DIM;
#pragma unroll
  for (int ks = 0; ks < 8; ++ks) {
    bf16x8 a0 = *(const bf16x8*)(a0p + ks * 32);
    bf16x8 a1 = *(const bf16x8*)(a1p + ks * 32);
    bf16x8 b0 = *(const bf16x8*)(b0p + ks * 32);
    bf16x8 b1 = *(const bf16x8*)(b1p + ks * 32);
    acc[0][0] = __builtin_amdgcn_mfma_f32_16x16x32_bf16(a0, b0, acc[0][0], 0, 0, 0);
    acc[0][1] = __builtin_amdgcn_mfma_f32_16x16x32_bf16(a0, b1, acc[0][1], 0, 0, 0);
    acc[1][0] = __builtin_amdgcn_mfma_f32_16x16x32_bf16(a1, b0, acc[1][0], 0, 0, 0);
    acc[1][1] = __builtin_amdgcn_mfma_f32_16x16x32_bf16(a1, b1, acc[1][1], 0, 0, 0);
  }
#pragma unroll
  for (int ot = 0; ot < 2; ++ot) {
    int o = o0 + ot * 16 + row16;
    float bv = lb[o];
#pragma unroll
    for (int it = 0; it < 2; ++it) {
#pragma unroll
      for (int r = 0; r < 4; ++r) {
        long i = i0 + it * 16 + grp * 4 + r;
        int bb = (int)(i >> 11);
        int n = (int)(i & (NPTS - 1));
        long off = ((long)bb * CIN + o) * NPTS + n;
        out[off] = acc[it][ot][r] + bv + x[off];
      }
    }
  }
}

// ---------------------------------------------------------------------------
extern "C" void kernel_launch(void* const* d_in, const int* in_sizes, int n_in,
                              void* d_out, int out_size, void* d_ws, size_t ws_size,
                              hipStream_t stream)
{
  const float* x     = (const float*)d_in[0];
  const float* pos   = (const float*)d_in[1];
  const float* ls_w  = (const float*)d_in[2];
  const float* ls_b  = (const float*)d_in[3];
  const float* kw    = (const float*)d_in[4];
  const float* kb    = (const float*)d_in[5];
  const float* qw    = (const float*)d_in[6];
  const float* qb    = (const float*)d_in[7];
  const float* vw    = (const float*)d_in[8];
  const float* vb    = (const float*)d_in[9];
  const float* pw1   = (const float*)d_in[10];
  const float* pb1   = (const float*)d_in[11];
  const float* pg    = (const float*)d_in[12];
  const float* pbeta = (const float*)d_in[13];
  const float* pmean = (const float*)d_in[14];
  const float* pvar  = (const float*)d_in[15];
  const float* pw2   = (const float*)d_in[16];
  const float* pb2   = (const float*)d_in[17];
  const float* aw1   = (const float*)d_in[18];
  const float* ab1   = (const float*)d_in[19];
  const float* ag    = (const float*)d_in[20];
  const float* abeta = (const float*)d_in[21];
  const float* amean = (const float*)d_in[22];
  const float* avar  = (const float*)d_in[23];
  const float* aw2   = (const float*)d_in[24];
  const float* ab2   = (const float*)d_in[25];
  const float* lw    = (const float*)d_in[26];
  const float* lb    = (const float*)d_in[27];

  char* ws = (char*)d_ws;
  size_t off = 0;
  auto alloc = [&](size_t bytes) -> void* {
    void* p = ws + off;
    off = (off + bytes + 255) & ~(size_t)255;
    return p;
  };

  bf16* ls_wb = (bf16*)alloc(32768 * 2);
  bf16* kwb   = (bf16*)alloc(65536 * 2);
  bf16* qwb   = (bf16*)alloc(65536 * 2);
  bf16* vwb   = (bf16*)alloc(65536 * 2);
  bf16* pw2b  = (bf16*)alloc(16384 * 2);
  bf16* aw1b  = (bf16*)alloc(262144 * 2);
  bf16* aw2b  = (bf16*)alloc(262144 * 2);
  bf16* lwb   = (bf16*)alloc(32768 * 2);
  float* pe_scale = (float*)alloc(64 * 4);
  float* pe_shift = (float*)alloc(64 * 4);
  float* at_scale = (float*)alloc(1024 * 4);
  float* at_shift = (float*)alloc(1024 * 4);
  int*  idx  = (int*)alloc((size_t)CC * 4);
  bf16* xT   = (bf16*)alloc((size_t)BN * CIN * 2);
  bf16* hT   = (bf16*)alloc((size_t)BN * DIM * 2);
  bf16* qT   = (bf16*)alloc((size_t)BN * DIM * 2);
  bf16* kT   = (bf16*)alloc((size_t)BN * DIM * 2);
  bf16* vTb  = (bf16*)alloc((size_t)BN * DIM * 2);
  bf16* aggT = (bf16*)alloc((size_t)BN * DIM * 2);

  // 1. prep
  prep_kernel<<<dim3((803904 + 255) / 256), 256, 0, stream>>>(
      ls_w, kw, qw, vw, pw2, aw1, aw2, lw,
      pb1, pg, pbeta, pmean, pvar, ab1, ag, abeta, amean, avar,
      ls_wb, kwb, qwb, vwb, pw2b, aw1b, aw2b, lwb,
      pe_scale, pe_shift, at_scale, at_shift);

  // 2. transpose x -> xT
  transpose_x_kernel<<<dim3(BN * CIN / 256), 256, 0, stream>>>(x, xT);

  // 3. KNN (wave-per-query)
  knn_kernel<<<dim3(BN / 4), 256, 0, stream>>>(pos, idx);

  // 4. hT = ls_w . x + ls_b
  gemmT_kernel<128, true><<<dim3(BN / 64, DIM / 64), 256, 0, stream>>>(xT, ls_wb, ls_b, hT, DIM);

  // 5. q,k,v projections (all bf16 out)
  gemmT_kernel<256, true><<<dim3(BN / 64, DIM / 64), 256, 0, stream>>>(hT, qwb, qb, qT, DIM);
  gemmT_kernel<256, true><<<dim3(BN / 64, DIM / 64), 256, 0, stream>>>(hT, kwb, kb, kT, DIM);
  gemmT_kernel<256, true><<<dim3(BN / 64, DIM / 64), 256, 0, stream>>>(hT, vwb, vb, vTb, DIM);

  // 6. fused attention (pe + u + MLP + softmax + agg)
  attn_fused_kernel<<<dim3(CC / 64), 256, 0, stream>>>(
      qT, kT, vTb, pos, idx, pw1, pe_scale, pe_shift, pw2b, pb2,
      aw1b, aw2b, at_scale, at_shift, ab2, aggT);

  // 7. y = lw . agg + lb + identity
  final_kernel<<<dim3(BN / 64, CIN / 64), 256, 0, stream>>>(aggT, lwb, lb, x, (float*)d_out);
}